// Round 1
// baseline (265.238 us; speedup 1.0000x reference)
//
#include <hip/hip_runtime.h>

#define NSER 1024
#define BB   1024
#define TT   512
#define NIN  28
#define NOUT 28
#define NTC  2
#define NS   4
#define MM   7
#define WW   457          // TT - NIN - NOUT + 1
#define SLEN 519          // MM + 1 + TT - 1
#define EMB  9            // 1 + 1 + MM

// out1: (WW, BB, 144) ; out2: (WW, BB, 28) ; out3: (BB, TT) ;
// out4: (BB, SLEN) ; out5: (WW, BB, 28)
#define OUT1_SZ (WW * BB * 144)
#define OUT2_SZ (WW * BB * 28)
#define OUT3_SZ (BB * TT)
#define OUT4_SZ (BB * SLEN)

// ---------------------------------------------------------------------------
// Kernel 1: exponential-smoothing scan. One thread per batch row.
// Critical path per step is ~1 FMA (q = y/seas_t has 7-step slack via the
// seasonal buffer; a_l*lev folds into one fma on lev).
// ---------------------------------------------------------------------------
__global__ void es_scan(const float* __restrict__ Y, const int* __restrict__ idxs,
                        const float* __restrict__ EW,
                        float* __restrict__ levels, float* __restrict__ seas) {
    int b = blockIdx.x * blockDim.x + threadIdx.x;
    if (b >= BB) return;
    const float* e = EW + idxs[b] * EMB;
    float lev_sms  = 1.0f / (1.0f + __expf(-e[0]));
    float seas_sms = 1.0f / (1.0f + __expf(-e[1]));
    float a_l = 1.0f - lev_sms;
    float a_s = 1.0f - seas_sms;

    float* seas_row = seas + b * SLEN;
    float  is0 = __expf(e[2]);
    float  buf[MM];
    seas_row[0] = is0;
#pragma unroll
    for (int k = 1; k < MM; ++k) {
        float v = __expf(e[2 + k]);
        seas_row[k] = v;
        buf[k - 1] = v;
    }
    buf[MM - 1] = is0;
    seas_row[MM] = is0;          // s0 appended after the 7 init seasonals

    const float* y_row = Y + b * TT;
    float* lev_row = levels + b * TT;
    float lev = y_row[0] / is0;
    lev_row[0] = lev;

    for (int t = 1; t < TT; ++t) {
        float y  = y_row[t];
        float st = buf[0];
        lev = lev_sms * __fdividef(y, st) + a_l * lev;
        float ns = seas_sms * __fdividef(y, lev) + a_s * st;
#pragma unroll
        for (int k = 0; k < MM - 1; ++k) buf[k] = buf[k + 1];
        buf[MM - 1] = ns;
        lev_row[t]        = lev;
        seas_row[MM + t]  = ns;
    }
}

// ---------------------------------------------------------------------------
// Kernel 2: windows_y_insample (WW, BB, 144) as float4 rows (36 per (w,b)).
//   c4  0..6  -> log(Y / (lev_end * seas))       (c = 0..27)
//   c4  7..20 -> X channel 0, offsets w+0..w+55
//   c4 21..34 -> X channel 1
//   c4 35     -> S[b, 0..4)
// ---------------------------------------------------------------------------
__global__ void win1(const float* __restrict__ Y, const float* __restrict__ X,
                     const float* __restrict__ S, const float* __restrict__ levels,
                     const float* __restrict__ seas, float4* __restrict__ out1) {
    const int total = WW * BB * 36;   // 16,846,848 float4
    int i      = blockIdx.x * blockDim.x + threadIdx.x;
    int stride = gridDim.x * blockDim.x;
    for (; i < total; i += stride) {
        int wb = i / 36;
        int c4 = i - wb * 36;
        int b  = wb & (BB - 1);
        int w  = wb >> 10;
        float4 v;
        if (c4 < 7) {
            int base = w + c4 * 4;
            float le = levels[b * TT + w + NIN - 1];
            const float* yr = Y    + b * TT;
            const float* sr = seas + b * SLEN;
            v.x = __logf(yr[base + 0] / (le * sr[base + 0]));
            v.y = __logf(yr[base + 1] / (le * sr[base + 1]));
            v.z = __logf(yr[base + 2] / (le * sr[base + 2]));
            v.w = __logf(yr[base + 3] / (le * sr[base + 3]));
        } else if (c4 < 21) {
            const float* xr = X + (b * 2 + 0) * TT + w + (c4 - 7) * 4;
            v.x = xr[0]; v.y = xr[1]; v.z = xr[2]; v.w = xr[3];
        } else if (c4 < 35) {
            const float* xr = X + (b * 2 + 1) * TT + w + (c4 - 21) * 4;
            v.x = xr[0]; v.y = xr[1]; v.z = xr[2]; v.w = xr[3];
        } else {
            v = *reinterpret_cast<const float4*>(S + b * NS);
        }
        out1[i] = v;
    }
}

// ---------------------------------------------------------------------------
// Kernel 3: windows_y_outsample + mask_w (same source index in Y / mask).
// ---------------------------------------------------------------------------
__global__ void win2(const float* __restrict__ Y, const float* __restrict__ mask,
                     float4* __restrict__ out2, float4* __restrict__ out5) {
    const int total = WW * BB * 7;    // 3,275,776 float4
    int i      = blockIdx.x * blockDim.x + threadIdx.x;
    int stride = gridDim.x * blockDim.x;
    for (; i < total; i += stride) {
        int wb = i / 7;
        int c4 = i - wb * 7;
        int b  = wb & (BB - 1);
        int w  = wb >> 10;
        int base = w + NIN + c4 * 4;       // <= 511
        const float* yr = Y    + b * TT + base;
        const float* mr = mask + b * TT + base;
        float4 vy, vm;
        vy.x = yr[0]; vy.y = yr[1]; vy.z = yr[2]; vy.w = yr[3];
        vm.x = mr[0]; vm.y = mr[1]; vm.z = mr[2]; vm.w = mr[3];
        out2[i] = vy;
        out5[i] = vm;
    }
}

extern "C" void kernel_launch(void* const* d_in, const int* in_sizes, int n_in,
                              void* d_out, int out_size, void* d_ws, size_t ws_size,
                              hipStream_t stream) {
    const float* S    = (const float*)d_in[0];
    const float* Y    = (const float*)d_in[1];
    const float* X    = (const float*)d_in[2];
    const int*   idxs = (const int*)d_in[3];
    const float* mask = (const float*)d_in[4];
    const float* EW   = (const float*)d_in[5];

    float* out  = (float*)d_out;
    float* out1 = out;
    float* out2 = out1 + OUT1_SZ;
    float* out3 = out2 + OUT2_SZ;        // levels
    float* out4 = out3 + OUT3_SZ;        // seasonalities
    float* out5 = out4 + OUT4_SZ;        // mask_w

    es_scan<<<(BB + 255) / 256, 256, 0, stream>>>(Y, idxs, EW, out3, out4);
    win1<<<2048, 256, 0, stream>>>(Y, X, S, out3, out4, (float4*)out1);
    win2<<<1024, 256, 0, stream>>>(Y, mask, (float4*)out2, (float4*)out5);
}

// Round 3
// 213.876 us; speedup vs baseline: 1.2401x; 1.2401x over previous
//
#include <hip/hip_runtime.h>

#define BB   1024
#define TT   512
#define NIN  28
#define NOUT 28
#define NS   4
#define MM   7
#define WW   457          // TT - NIN - NOUT + 1
#define SLEN 519          // MM + 1 + TT - 1
#define EMB  9            // 1 + 1 + MM

#define OUT1_SZ (WW * BB * 144)
#define OUT2_SZ (WW * BB * 28)
#define OUT3_SZ (BB * TT)
#define OUT4_SZ (BB * SLEN)

#define CH   32
#define NCH  (TT / CH)    // 16

// ---------------------------------------------------------------------------
// Kernel 1: ES scan, LDS-staged for coalescing. 4 blocks x 256 threads.
// Per chunk: coalesced global->LDS (padded stride 33 => 2-way bank = free),
// LDS->reg batch copy, 32 recurrence steps in registers (fully unrolled,
// static indexing), LDS staging of lev/seas, coalesced store.
// ---------------------------------------------------------------------------
__global__ __launch_bounds__(256) void es_scan(const float* __restrict__ Y,
        const int* __restrict__ idxs, const float* __restrict__ EW,
        float* __restrict__ levels, float* __restrict__ seas) {
    __shared__ float yl[256][CH + 1];   // y, overwritten in-place by lev
    __shared__ float se[256][CH + 1];   // new seasonals
    const int tid = threadIdx.x;
    const int b0  = blockIdx.x << 8;
    const int b   = b0 + tid;

    const float* e = EW + idxs[b] * EMB;
    const float lev_sms  = 1.0f / (1.0f + __expf(-e[0]));
    const float seas_sms = 1.0f / (1.0f + __expf(-e[1]));
    const float a_l = 1.0f - lev_sms;
    const float a_s = 1.0f - seas_sms;

    float buf[MM];
    const float is0 = __expf(e[2]);
    {
        float* srow = seas + b * SLEN;
        srow[0] = is0;
#pragma unroll
        for (int k = 1; k < MM; ++k) {
            float v = __expf(e[2 + k]);
            srow[k] = v;
            buf[k - 1] = v;
        }
        buf[MM - 1] = is0;
    }

    float lev = 0.0f;

#define ES_STEP(TTI)                                                        \
    {                                                                       \
        float y  = yreg[TTI];                                               \
        float st = buf[0];                                                  \
        lev = lev_sms * __fdividef(y, st) + a_l * lev;                      \
        float ns = seas_sms * __fdividef(y, lev) + a_s * st;                \
        buf[0] = buf[1]; buf[1] = buf[2]; buf[2] = buf[3];                  \
        buf[3] = buf[4]; buf[4] = buf[5]; buf[5] = buf[6];                  \
        buf[6] = ns;                                                        \
        yl[tid][TTI] = lev;                                                 \
        se[tid][TTI] = ns;                                                  \
    }

    for (int c = 0; c < NCH; ++c) {
        __syncthreads();   // previous chunk's cooperative store done
        // cooperative load: Y[b0..b0+255][c*CH .. +CH) -> yl (coalesced)
#pragma unroll
        for (int k = 0; k < CH / 4; ++k) {        // 8 float4 per thread
            int flat = (k << 8) + tid;            // 0..2047
            int r = flat >> 3;                    // 8 float4 per row
            int q = flat & 7;
            float4 v = *reinterpret_cast<const float4*>(
                Y + (b0 + r) * TT + c * CH + (q << 2));
            float* dst = &yl[r][q << 2];
            dst[0] = v.x; dst[1] = v.y; dst[2] = v.z; dst[3] = v.w;
        }
        __syncthreads();

        float yreg[CH];
#pragma unroll
        for (int tt = 0; tt < CH; ++tt) yreg[tt] = yl[tid][tt];

        if (c == 0) {
            lev = __fdividef(yreg[0], is0);
            yl[tid][0] = lev;
            se[tid][0] = is0;                     // s0 at seas index MM
#pragma unroll
            for (int tt = 1; tt < CH; ++tt) ES_STEP(tt)
        } else {
#pragma unroll
            for (int tt = 0; tt < CH; ++tt) ES_STEP(tt)
        }
        __syncthreads();

        // cooperative store (coalesced)
#pragma unroll
        for (int k = 0; k < CH; ++k) {
            int flat = (k << 8) + tid;            // 0..8191
            int r    = flat >> 5;                 // 32 cols per row
            int col  = flat & 31;
            levels[(b0 + r) * TT   + c * CH + col]       = yl[r][col];
            seas  [(b0 + r) * SLEN + MM + c * CH + col]  = se[r][col];
        }
    }
#undef ES_STEP
}

// ---------------------------------------------------------------------------
// Kernel 2: all streaming work in one grid-stride pass (float4 units):
//   region A: out1 cols 7..35  (X windows + statics)          NXS items
//   region B: out1 cols 0..6   (log insample, reads lev/seas) NLOG items
//   region C: out2 + out5      (outsample Y + mask)           NW2 items
// ---------------------------------------------------------------------------
#define NXS  (WW * BB * 29)
#define NLOG (WW * BB * 7)
#define NW2  (WW * BB * 7)
#define NTOT (NXS + NLOG + NW2)

__global__ __launch_bounds__(256) void main_stream(const float* __restrict__ S,
        const float* __restrict__ Y, const float* __restrict__ X,
        const float* __restrict__ mask, const float* __restrict__ levels,
        const float* __restrict__ seas, float4* __restrict__ out1,
        float4* __restrict__ out2, float4* __restrict__ out5) {
    int i = blockIdx.x * blockDim.x + threadIdx.x;
    const int stride = gridDim.x * blockDim.x;
    for (; i < NTOT; i += stride) {
        if (i < NXS) {
            int wb = i / 29;
            int j  = i - wb * 29;                 // 0..28
            int b  = wb & (BB - 1);
            int w  = wb >> 10;
            float4 v;
            if (j < 14) {
                const float* xr = X + (b * 2) * TT + w + (j << 2);
                v.x = xr[0]; v.y = xr[1]; v.z = xr[2]; v.w = xr[3];
            } else if (j < 28) {
                const float* xr = X + (b * 2 + 1) * TT + w + ((j - 14) << 2);
                v.x = xr[0]; v.y = xr[1]; v.z = xr[2]; v.w = xr[3];
            } else {
                v = *reinterpret_cast<const float4*>(S + b * NS);
            }
            out1[wb * 36 + 7 + j] = v;
        } else if (i < NXS + NLOG) {
            int k  = i - NXS;
            int wb = k / 7;
            int j  = k - wb * 7;                  // 0..6
            int b  = wb & (BB - 1);
            int w  = wb >> 10;
            int base = w + (j << 2);
            float le = levels[b * TT + w + NIN - 1];
            const float* yr = Y    + b * TT   + base;
            const float* sr = seas + b * SLEN + base;
            float4 v;
            v.x = __logf(__fdividef(yr[0], le * sr[0]));
            v.y = __logf(__fdividef(yr[1], le * sr[1]));
            v.z = __logf(__fdividef(yr[2], le * sr[2]));
            v.w = __logf(__fdividef(yr[3], le * sr[3]));
            out1[wb * 36 + j] = v;
        } else {
            int k  = i - (NXS + NLOG);
            int wb = k / 7;
            int j  = k - wb * 7;                  // 0..6
            int b  = wb & (BB - 1);
            int w  = wb >> 10;
            int base = w + NIN + (j << 2);
            const float* yr = Y    + b * TT + base;
            const float* mr = mask + b * TT + base;
            float4 vy, vm;
            vy.x = yr[0]; vy.y = yr[1]; vy.z = yr[2]; vy.w = yr[3];
            vm.x = mr[0]; vm.y = mr[1]; vm.z = mr[2]; vm.w = mr[3];
            out2[wb * 7 + j] = vy;
            out5[wb * 7 + j] = vm;
        }
    }
}

extern "C" void kernel_launch(void* const* d_in, const int* in_sizes, int n_in,
                              void* d_out, int out_size, void* d_ws, size_t ws_size,
                              hipStream_t stream) {
    const float* S    = (const float*)d_in[0];
    const float* Y    = (const float*)d_in[1];
    const float* X    = (const float*)d_in[2];
    const int*   idxs = (const int*)d_in[3];
    const float* mask = (const float*)d_in[4];
    const float* EW   = (const float*)d_in[5];

    float* out  = (float*)d_out;
    float* out1 = out;
    float* out2 = out1 + OUT1_SZ;
    float* out3 = out2 + OUT2_SZ;        // levels
    float* out4 = out3 + OUT3_SZ;        // seasonalities
    float* out5 = out4 + OUT4_SZ;        // mask_w

    es_scan<<<BB / 256, 256, 0, stream>>>(Y, idxs, EW, out3, out4);
    main_stream<<<2048, 256, 0, stream>>>(S, Y, X, mask, out3, out4,
                                          (float4*)out1, (float4*)out2,
                                          (float4*)out5);
}

// Round 4
// 133.351 us; speedup vs baseline: 1.9890x; 1.6039x over previous
//
#include <hip/hip_runtime.h>

#define BB   1024
#define TT   512
#define NIN  28
#define NOUT 28
#define NS   4
#define MM   7
#define WW   457          // TT - NIN - NOUT + 1
#define SLEN 519          // MM + 1 + TT - 1
#define EMB  9            // 1 + 1 + MM

#define OUT1_SZ (WW * BB * 144)
#define OUT2_SZ (WW * BB * 28)
#define OUT3_SZ (BB * TT)
#define OUT4_SZ (BB * SLEN)

#define CH   32
#define NCH  (TT / CH)    // 16

typedef float f4 __attribute__((ext_vector_type(4)));

__device__ __forceinline__ f4 ld4u(const float* p) {   // 4B-aligned 16B load
    f4 v;
    __builtin_memcpy(&v, p, sizeof(f4));
    return v;
}

// ---------------------------------------------------------------------------
// Kernel 1: ES scan. 16 blocks x 64 threads (1 wave/block, 16 CUs).
// Global->reg prefetch double-buffer hides load latency across chunks;
// LDS staging keeps global loads/stores coalesced.
// ---------------------------------------------------------------------------
__global__ __launch_bounds__(64) void es_scan(const float* __restrict__ Y,
        const int* __restrict__ idxs, const float* __restrict__ EW,
        float* __restrict__ levels, float* __restrict__ seas) {
    __shared__ float yl[64][CH + 1];
    __shared__ float se[64][CH + 1];
    const int tid = threadIdx.x;
    const int b0  = blockIdx.x << 6;
    const int b   = b0 + tid;

    const float* e = EW + idxs[b] * EMB;
    const float lev_sms  = 1.0f / (1.0f + __expf(-e[0]));
    const float seas_sms = 1.0f / (1.0f + __expf(-e[1]));
    const float a_l = 1.0f - lev_sms;
    const float a_s = 1.0f - seas_sms;

    float buf[MM];
    const float is0 = __expf(e[2]);
    {
        float* srow = seas + b * SLEN;
        srow[0] = is0;
#pragma unroll
        for (int k = 1; k < MM; ++k) {
            float v = __expf(e[2 + k]);
            srow[k] = v;
            buf[k - 1] = v;
        }
        buf[MM - 1] = is0;
    }

    // prefetch chunk 0 (coalesced-ish: 8 lanes cover 128B per row)
    f4 pf[8];
#pragma unroll
    for (int k = 0; k < 8; ++k) {
        int flat = (k << 6) + tid;                // 0..511
        int r = flat >> 3, q = flat & 7;
        pf[k] = *reinterpret_cast<const f4*>(Y + (b0 + r) * TT + (q << 2));
    }

    float lev = 0.0f;

#define ES_STEP(TTI)                                                        \
    {                                                                       \
        float y  = yreg[TTI];                                               \
        float st = buf[0];                                                  \
        lev = lev_sms * __fdividef(y, st) + a_l * lev;                      \
        float ns = seas_sms * __fdividef(y, lev) + a_s * st;                \
        buf[0] = buf[1]; buf[1] = buf[2]; buf[2] = buf[3];                  \
        buf[3] = buf[4]; buf[4] = buf[5]; buf[5] = buf[6];                  \
        buf[6] = ns;                                                        \
        yl[tid][TTI] = lev;                                                 \
        se[tid][TTI] = ns;                                                  \
    }

    for (int c = 0; c < NCH; ++c) {
        __syncthreads();   // prev chunk's coop-store reads done
        // deposit prefetched chunk into LDS
#pragma unroll
        for (int k = 0; k < 8; ++k) {
            int flat = (k << 6) + tid;
            int r = flat >> 3, q = flat & 7;
            float* dst = &yl[r][q << 2];
            dst[0] = pf[k].x; dst[1] = pf[k].y; dst[2] = pf[k].z; dst[3] = pf[k].w;
        }
        __syncthreads();
        // issue next chunk's loads (latency hidden under compute)
        if (c < NCH - 1) {
#pragma unroll
            for (int k = 0; k < 8; ++k) {
                int flat = (k << 6) + tid;
                int r = flat >> 3, q = flat & 7;
                pf[k] = *reinterpret_cast<const f4*>(
                    Y + (b0 + r) * TT + (c + 1) * CH + (q << 2));
            }
        }

        float yreg[CH];
#pragma unroll
        for (int tt = 0; tt < CH; ++tt) yreg[tt] = yl[tid][tt];

        if (c == 0) {
            lev = __fdividef(yreg[0], is0);
            yl[tid][0] = lev;
            se[tid][0] = is0;                     // s0 at seas index MM
#pragma unroll
            for (int tt = 1; tt < CH; ++tt) ES_STEP(tt)
        } else {
#pragma unroll
            for (int tt = 0; tt < CH; ++tt) ES_STEP(tt)
        }
        __syncthreads();

        // cooperative coalesced store: 2 rows x 128B per wave-instr
#pragma unroll
        for (int k = 0; k < CH; ++k) {
            int flat = (k << 6) + tid;            // 0..2047
            int r    = flat >> 5;                 // 0..63
            int col  = flat & 31;
            levels[(b0 + r) * TT   + c * CH + col]      = yl[r][col];
            seas  [(b0 + r) * SLEN + MM + c * CH + col] = se[r][col];
        }
    }
#undef ES_STEP
}

// ---------------------------------------------------------------------------
// Kernel 2: all streaming work, one grid-stride pass over float4 units.
//   region A: out1 f4 cols 8..35 (X chan0 4..55, chan1 0..55, S) — lines 2..8
//   region B: out1 f4 cols 0..7  (log insample + X chan0 0..3)   — lines 0..1
//   region C: out2 + out5
// Line-ownership: no cache line of out1 is written by two regions.
// ---------------------------------------------------------------------------
#define NA (WW * BB * 28)
#define NB (WW * BB * 8)
#define NC (WW * BB * 7)
#define NTOT (NA + NB + NC)

__global__ __launch_bounds__(256) void main_stream(const float* __restrict__ S,
        const float* __restrict__ Y, const float* __restrict__ X,
        const float* __restrict__ mask, const float* __restrict__ levels,
        const float* __restrict__ seas, f4* __restrict__ out1,
        f4* __restrict__ out2, f4* __restrict__ out5) {
    int i = blockIdx.x * blockDim.x + threadIdx.x;
    const int stride = gridDim.x * blockDim.x;
    for (; i < NTOT; i += stride) {
        if (i < NA) {
            int wb = i / 28;
            int j  = i - wb * 28;                 // 0..27
            int b  = wb & (BB - 1);
            int w  = wb >> 10;
            f4 v;
            if (j < 13) {                         // chan0, offsets w+4..w+55
                v = ld4u(X + (b * 2) * TT + w + ((j + 1) << 2));
            } else if (j < 27) {                  // chan1, offsets w+0..w+55
                v = ld4u(X + (b * 2 + 1) * TT + w + ((j - 13) << 2));
            } else {                              // statics
                v = *reinterpret_cast<const f4*>(S + b * NS);
            }
            __builtin_nontemporal_store(v, &out1[wb * 36 + 8 + j]);
        } else if (i < NA + NB) {
            int t  = i - NA;
            int wb = t >> 3;
            int j  = t & 7;                       // 0..7
            int b  = wb & (BB - 1);
            int w  = wb >> 10;
            f4 v;
            if (j < 7) {                          // log insample
                int base = w + (j << 2);
                float le = levels[b * TT + w + NIN - 1];
                f4 yv = ld4u(Y    + b * TT   + base);
                f4 sv = ld4u(seas + b * SLEN + base);
                v.x = __logf(__fdividef(yv.x, le * sv.x));
                v.y = __logf(__fdividef(yv.y, le * sv.y));
                v.z = __logf(__fdividef(yv.z, le * sv.z));
                v.w = __logf(__fdividef(yv.w, le * sv.w));
            } else {                              // X chan0 offsets w+0..3
                v = ld4u(X + (b * 2) * TT + w);
            }
            __builtin_nontemporal_store(v, &out1[wb * 36 + j]);
        } else {
            int t  = i - (NA + NB);
            int wb = t / 7;
            int j  = t - wb * 7;                  // 0..6
            int b  = wb & (BB - 1);
            int w  = wb >> 10;
            int base = w + NIN + (j << 2);
            f4 vy = ld4u(Y    + b * TT + base);
            f4 vm = ld4u(mask + b * TT + base);
            __builtin_nontemporal_store(vy, &out2[wb * 7 + j]);
            __builtin_nontemporal_store(vm, &out5[wb * 7 + j]);
        }
    }
}

extern "C" void kernel_launch(void* const* d_in, const int* in_sizes, int n_in,
                              void* d_out, int out_size, void* d_ws, size_t ws_size,
                              hipStream_t stream) {
    const float* S    = (const float*)d_in[0];
    const float* Y    = (const float*)d_in[1];
    const float* X    = (const float*)d_in[2];
    const int*   idxs = (const int*)d_in[3];
    const float* mask = (const float*)d_in[4];
    const float* EW   = (const float*)d_in[5];

    float* out  = (float*)d_out;
    float* out1 = out;
    float* out2 = out1 + OUT1_SZ;
    float* out3 = out2 + OUT2_SZ;        // levels
    float* out4 = out3 + OUT3_SZ;        // seasonalities
    float* out5 = out4 + OUT4_SZ;        // mask_w

    es_scan<<<16, 64, 0, stream>>>(Y, idxs, EW, out3, out4);
    main_stream<<<2048, 256, 0, stream>>>(S, Y, X, mask, out3, out4,
                                          (f4*)out1, (f4*)out2, (f4*)out5);
}